// Round 1
// baseline (1342.915 us; speedup 1.0000x reference)
//
#include <hip/hip_runtime.h>
#include <float.h>

#define VDIM 50257
#define NT   256
#define CAP  4096
#define TRIG 2048

// monotone key: larger float <-> larger unsigned key (no NaNs in this data)
__device__ __forceinline__ unsigned f2key(float f){
  unsigned ix = __float_as_uint(f);
  return (ix & 0x80000000u) ? ~ix : (ix | 0x80000000u);
}
__device__ __forceinline__ float key2f(unsigned k){
  return (k & 0x80000000u) ? __uint_as_float(k & 0x7FFFFFFFu)
                           : __uint_as_float(~k);
}
__device__ __forceinline__ float gnoise(float uu){
  // -log(-log(u+eps)+eps)
  return -__logf(-__logf(uu + 1e-10f) + 1e-10f);
}

// exact k-th largest of cand[0..n) via 8-bit radix select; all 256 threads participate
__device__ float kth_largest(float* cand, int n, int k, int* hist,
                             int* s_dig, int* s_krem){
  unsigned prefix = 0u, maskb = 0u;
  int kr = k;
  const int tid = threadIdx.x;
  for (int shift = 24; shift >= 0; shift -= 8){
    hist[tid] = 0;
    __syncthreads();
    for (int i = tid; i < n; i += NT){
      unsigned key = f2key(cand[i]);
      if ((key & maskb) == prefix)
        atomicAdd(&hist[(key >> shift) & 0xFFu], 1);
    }
    __syncthreads();
    if (tid == 0){
      int c = 0, d = 255;
      for (; d >= 0; --d){ c += hist[d]; if (c >= kr) break; }
      if (d < 0) d = 0;
      *s_dig  = d;
      *s_krem = kr - (c - hist[d]);
    }
    __syncthreads();
    int d = *s_dig;
    kr = *s_krem; if (kr < 1) kr = 1;
    prefix |= ((unsigned)d) << shift;
    maskb  |= (0xFFu << shift);
    __syncthreads();
  }
  return key2f(prefix);
}

// raise T0 to exact k-th largest of buffer, keep only elements >= it
__device__ void compact_buf(float* cand, int* hist, int* s_dig, int* s_krem,
                            int* s_cnt, float* s_T0, int kk){
  int n = *s_cnt; if (n > CAP) n = CAP;
  float tk = kth_largest(cand, n, kk, hist, s_dig, s_krem);
  float keep[16]; int m = 0;
  for (int i = threadIdx.x; i < n; i += NT){
    float v = cand[i];
    if (v >= tk && m < 16) keep[m++] = v;
  }
  __syncthreads();
  if (threadIdx.x == 0){ *s_cnt = 0; *s_T0 = tk; }
  __syncthreads();
  for (int j = 0; j < m; ++j){
    int p = atomicAdd(s_cnt, 1);
    if (p < TRIG) cand[p] = keep[j];
  }
}

__global__ __launch_bounds__(NT)
void gumbel_topk_softmax(const float* __restrict__ logits,
                         const float* __restrict__ u,
                         const int* __restrict__ kptr,
                         float* __restrict__ out)
{
  __shared__ float cand[CAP];     // 16 KB candidate buffer (superset of row top-k)
  __shared__ int   hist[NT];      // radix histogram
  __shared__ float redf[8];
  __shared__ int   s_cnt, s_dig, s_krem;
  __shared__ float s_T0;

  const int tid = threadIdx.x;
  const size_t rbase = (size_t)blockIdx.x * VDIM;
  const float* lrow = logits + rbase;
  const float* urow = u + rbase;
  float* orow = out + rbase;

  // V is odd -> per-row float4 alignment peel
  const int head  = (int)((4 - (rbase & 3)) & 3);
  const int nv4   = (VDIM - head) >> 2;
  const int tailn = (VDIM - head) & 3;
  const int nedge = head + tailn;
  const float4* l4 = (const float4*)(lrow + head);
  const float4* u4 = (const float4*)(urow + head);
  float4* o4 = (float4*)(orow + head);

  int kk = *kptr;
  if (kk < 1) kk = 1;
  if (kk > TRIG) kk = TRIG;

  if (tid == 0){ s_cnt = 0; s_T0 = -FLT_MAX; }
  __syncthreads();

  float maxl = -FLT_MAX;

  // ---- Phase 1: scan, adaptive top-k candidate collection ----
  if (tid < nedge){
    int idx = (tid < head) ? tid : ((nv4 << 2) + tid);
    float l = lrow[idx];
    float g = l + gnoise(urow[idx]);
    maxl = fmaxf(maxl, l);
    int p = atomicAdd(&s_cnt, 1);
    if (p < CAP) cand[p] = g;
  }
  __syncthreads();

  for (int b = 0; b < nv4; b += NT * 2){
    float t0 = s_T0;
    #pragma unroll
    for (int j = 0; j < 2; ++j){
      int i = b + tid + j * NT;
      if (i < nv4){
        float4 lv = l4[i];
        float4 uv = u4[i];
        float g0 = lv.x + gnoise(uv.x);
        float g1 = lv.y + gnoise(uv.y);
        float g2 = lv.z + gnoise(uv.z);
        float g3 = lv.w + gnoise(uv.w);
        maxl = fmaxf(maxl, fmaxf(fmaxf(lv.x, lv.y), fmaxf(lv.z, lv.w)));
        if (g0 >= t0){ int p = atomicAdd(&s_cnt, 1); if (p < CAP) cand[p] = g0; }
        if (g1 >= t0){ int p = atomicAdd(&s_cnt, 1); if (p < CAP) cand[p] = g1; }
        if (g2 >= t0){ int p = atomicAdd(&s_cnt, 1); if (p < CAP) cand[p] = g2; }
        if (g3 >= t0){ int p = atomicAdd(&s_cnt, 1); if (p < CAP) cand[p] = g3; }
      }
    }
    __syncthreads();
    if (s_cnt > TRIG){
      compact_buf(cand, hist, &s_dig, &s_krem, &s_cnt, &s_T0, kk);
    }
    __syncthreads();
  }

  // exact threshold = k-th largest of candidate buffer (== k-th largest of row)
  int n = s_cnt; if (n > CAP) n = CAP;
  float thr = kth_largest(cand, n, kk, hist, &s_dig, &s_krem);

  // block max of logits -> stability offset M (any upper bound of masked works)
  #pragma unroll
  for (int off = 32; off > 0; off >>= 1)
    maxl = fmaxf(maxl, __shfl_down(maxl, off));
  if ((tid & 63) == 0) redf[tid >> 6] = maxl;
  __syncthreads();
  float M = fmaxf(fmaxf(redf[0], redf[1]), fmaxf(redf[2], redf[3]));
  if (M < 0.f) M = 0.f;
  __syncthreads();

  // ---- Phase 2: denominator ----
  float sl = 0.f;
  if (tid < nedge){
    int idx = (tid < head) ? tid : ((nv4 << 2) + tid);
    float l = lrow[idx];
    float g = l + gnoise(urow[idx]);
    float sm = 1.f / (1.f + __expf(thr - g));
    sl += __expf(l * sm - M);
  }
  for (int i = tid; i < nv4; i += NT){
    float4 lv = l4[i];
    float4 uv = u4[i];
    float g0 = lv.x + gnoise(uv.x);
    float g1 = lv.y + gnoise(uv.y);
    float g2 = lv.z + gnoise(uv.z);
    float g3 = lv.w + gnoise(uv.w);
    sl += __expf(lv.x * (1.f / (1.f + __expf(thr - g0))) - M);
    sl += __expf(lv.y * (1.f / (1.f + __expf(thr - g1))) - M);
    sl += __expf(lv.z * (1.f / (1.f + __expf(thr - g2))) - M);
    sl += __expf(lv.w * (1.f / (1.f + __expf(thr - g3))) - M);
  }
  #pragma unroll
  for (int off = 32; off > 0; off >>= 1)
    sl += __shfl_down(sl, off);
  if ((tid & 63) == 0) redf[4 + (tid >> 6)] = sl;
  __syncthreads();
  float inv = 1.f / (redf[4] + redf[5] + redf[6] + redf[7]);

  // ---- Phase 3: write softmax ----
  if (tid < nedge){
    int idx = (tid < head) ? tid : ((nv4 << 2) + tid);
    float l = lrow[idx];
    float g = l + gnoise(urow[idx]);
    float sm = 1.f / (1.f + __expf(thr - g));
    orow[idx] = __expf(l * sm - M) * inv;
  }
  for (int i = tid; i < nv4; i += NT){
    float4 lv = l4[i];
    float4 uv = u4[i];
    float4 ov;
    {
      float g = lv.x + gnoise(uv.x);
      ov.x = __expf(lv.x * (1.f / (1.f + __expf(thr - g))) - M) * inv;
    }
    {
      float g = lv.y + gnoise(uv.y);
      ov.y = __expf(lv.y * (1.f / (1.f + __expf(thr - g))) - M) * inv;
    }
    {
      float g = lv.z + gnoise(uv.z);
      ov.z = __expf(lv.z * (1.f / (1.f + __expf(thr - g))) - M) * inv;
    }
    {
      float g = lv.w + gnoise(uv.w);
      ov.w = __expf(lv.w * (1.f / (1.f + __expf(thr - g))) - M) * inv;
    }
    o4[i] = ov;
  }
}

extern "C" void kernel_launch(void* const* d_in, const int* in_sizes, int n_in,
                              void* d_out, int out_size, void* d_ws, size_t ws_size,
                              hipStream_t stream) {
  const float* logits = (const float*)d_in[0];
  const float* u      = (const float*)d_in[1];
  const int*   kptr   = (const int*)d_in[2];
  float* out = (float*)d_out;
  int B = in_sizes[0] / VDIM;   // 2048
  gumbel_topk_softmax<<<B, NT, 0, stream>>>(logits, u, kptr, out);
}